// Round 2
// baseline (5997.671 us; speedup 1.0000x reference)
//
#include <hip/hip_runtime.h>
#include <hip/hip_bf16.h>

typedef short bf16x8 __attribute__((ext_vector_type(8)));
typedef float f32x4 __attribute__((ext_vector_type(4)));
using bf16 = __hip_bfloat16;

// ---------------------------------------------------------------- utilities
static __device__ __forceinline__ float gelu_f(float x) {
    float x3 = x * x * x;
    return 0.5f * x * (1.0f + tanhf(0.7978845608028654f * (x + 0.044715f * x3)));
}

// ---------------------------------------------------------------- transpose + downcast (f32 -> bf16), batched over z
__global__ __launch_bounds__(256) void transpose_f32_bf16(const float* __restrict__ in,
                                                          bf16* __restrict__ out,
                                                          int R, int C) {
    __shared__ float tile[32][33];
    size_t zo = (size_t)blockIdx.z * R * C;
    int c0 = blockIdx.x * 32, r0 = blockIdx.y * 32;
    int tx = threadIdx.x & 31, ty = threadIdx.x >> 5;
    #pragma unroll
    for (int i = 0; i < 32; i += 8) {
        int r = r0 + ty + i, c = c0 + tx;
        if (r < R && c < C) tile[ty + i][tx] = in[zo + (size_t)r * C + c];
    }
    __syncthreads();
    #pragma unroll
    for (int i = 0; i < 32; i += 8) {
        int c = c0 + ty + i, r = r0 + tx;
        if (c < C && r < R) out[zo + (size_t)c * R + r] = __float2bfloat16(tile[tx][ty + i]);
    }
}

// ---------------------------------------------------------------- patch embedding + positional encoding
// one block per output row (b*240 + l); h[row][d] = sum_i x[b,(j*16+i)*k] * Wemb[i][d] + pe[j*k][d]
__global__ __launch_bounds__(256) void embed_kernel(const float* __restrict__ x_enc,
                                                    const float* __restrict__ W_emb, // [16][512]
                                                    bf16* __restrict__ h) {
    int row = blockIdx.x;
    int b = row / 240, l = row - b * 240;
    int s = (l < 16) ? 0 : (l < 48) ? 1 : (l < 112) ? 2 : 3;
    int len = 16 << s;
    int off = len - 16;           // 0,16,48,112
    int kk = 8 >> s;              // 8,4,2,1
    int j = l - off;
    int bs_i = b >> 5, c_i = b & 31;
    __shared__ float xv[16];
    int t = threadIdx.x;
    if (t < 16) {
        int tau = (j * 16 + t) * kk;
        xv[t] = x_enc[((size_t)bs_i * 2048 + tau) * 32 + c_i];
    }
    __syncthreads();
    int pe_row = j * kk;
    const float NEG2LN = -0.035977892078032f; // -2*ln(10000)/512
    for (int d = t; d < 512; d += 256) {
        float acc = 0.f;
        #pragma unroll
        for (int i = 0; i < 16; ++i) acc += xv[i] * W_emb[i * 512 + d];
        int di = d >> 1;
        float ang = (float)pe_row * expf((float)di * NEG2LN);
        float pos = (d & 1) ? cosf(ang) : sinf(ang);
        h[(size_t)row * 512 + d] = __float2bfloat16(acc + pos);
    }
}

// ---------------------------------------------------------------- GEMM: C[M,N] = A[M,K] @ Bt[N,K]^T + bias (+gelu)
// 128x128 tile, BK=32, 4 waves each 64x64 via 4x4 mfma_f32_16x16x32_bf16.
#define GBM 128
#define GBN 128
#define GBK 32
#define GLDA 56   // padded LDS stride (112 B = odd multiple of 16 B -> conflict-free b128)

__global__ __launch_bounds__(256) void gemm_bt(const bf16* __restrict__ A,
                                               const bf16* __restrict__ Bt,
                                               const float* __restrict__ bias,
                                               bf16* __restrict__ C,
                                               int M, int N, int K, int act) {
    __shared__ bf16 As[GBM * GLDA];
    __shared__ bf16 Bs[GBN * GLDA];
    const int t = threadIdx.x;
    const int wave = t >> 6, lane = t & 63;
    const int quad = lane >> 4, l16 = lane & 15;
    const int m0 = blockIdx.y * GBM, n0 = blockIdx.x * GBN;
    const int wm = (wave >> 1) * 64, wn = (wave & 1) * 64;

    f32x4 acc[4][4];
    #pragma unroll
    for (int a = 0; a < 4; ++a)
        #pragma unroll
        for (int b = 0; b < 4; ++b)
            #pragma unroll
            for (int r = 0; r < 4; ++r) acc[a][b][r] = 0.0f;

    const int lrow = t >> 2;        // 0..63
    const int lkc = (t & 3) * 8;    // 0,8,16,24

    for (int k0 = 0; k0 < K; k0 += GBK) {
        __syncthreads();
        #pragma unroll
        for (int p = 0; p < 2; ++p) {
            int r = lrow + p * 64;
            *(uint4*)(&As[r * GLDA + lkc]) =
                *(const uint4*)(A + (size_t)(m0 + r) * K + k0 + lkc);
            *(uint4*)(&Bs[r * GLDA + lkc]) =
                *(const uint4*)(Bt + (size_t)(n0 + r) * K + k0 + lkc);
        }
        __syncthreads();
        bf16x8 af[4], bfr[4];
        #pragma unroll
        for (int mi = 0; mi < 4; ++mi)
            af[mi] = *(const bf16x8*)(&As[(wm + mi * 16 + l16) * GLDA + quad * 8]);
        #pragma unroll
        for (int ni = 0; ni < 4; ++ni)
            bfr[ni] = *(const bf16x8*)(&Bs[(wn + ni * 16 + l16) * GLDA + quad * 8]);
        #pragma unroll
        for (int mi = 0; mi < 4; ++mi)
            #pragma unroll
            for (int ni = 0; ni < 4; ++ni)
                acc[mi][ni] = __builtin_amdgcn_mfma_f32_16x16x32_bf16(af[mi], bfr[ni],
                                                                     acc[mi][ni], 0, 0, 0);
    }

    #pragma unroll
    for (int ni = 0; ni < 4; ++ni) {
        int col = n0 + wn + ni * 16 + l16;
        float bv = bias[col];
        #pragma unroll
        for (int mi = 0; mi < 4; ++mi) {
            #pragma unroll
            for (int r = 0; r < 4; ++r) {
                int row = m0 + wm + mi * 16 + quad * 4 + r;
                float x = acc[mi][ni][r] + bv;
                if (act) x = gelu_f(x);
                C[(size_t)row * N + col] = __float2bfloat16(x);
            }
        }
    }
}

// ---------------------------------------------------------------- segment attention
// one block per (b, head, seg). len in {16,32,64,128}, hd=64.
__global__ __launch_bounds__(256) void attn_kernel(const bf16* __restrict__ q,
                                                   const bf16* __restrict__ k,
                                                   const bf16* __restrict__ v,
                                                   bf16* __restrict__ o) {
    __shared__ float Kt[64][132];   // K transposed, fp32
    __shared__ bf16  Vs[128][64];
    __shared__ float Qs[16][68];    // one 16-row slab of Q (scaled)
    __shared__ float S[16][132];    // scores / probs for the slab

    int idx = blockIdx.x;
    int s = idx & 3, hh = (idx >> 2) & 7, b = idx >> 5;
    int len = 16 << s;
    int off = len - 16;
    int t = threadIdx.x;
    size_t base = (((size_t)b * 240 + off) * 512) + hh * 64;

    // load K (transposed) and V
    {
        int jj0 = t >> 3;
        int d0 = (t & 7) * 8;
        for (int jj = jj0; jj < len; jj += 32) {
            uint4 kv = *(const uint4*)(k + base + (size_t)jj * 512 + d0);
            const bf16* kp = (const bf16*)&kv;
            #pragma unroll
            for (int e = 0; e < 8; ++e) Kt[d0 + e][jj] = __bfloat162float(kp[e]);
            *(uint4*)(&Vs[jj][d0]) = *(const uint4*)(v + base + (size_t)jj * 512 + d0);
        }
    }

    int nslab = len >> 4;
    for (int sl = 0; sl < nslab; ++sl) {
        __syncthreads();
        if (t < 128) {  // load Q slab, fold in softmax scale 1/8
            int qi = t >> 3, d0 = (t & 7) * 8;
            uint4 qv = *(const uint4*)(q + base + (size_t)(sl * 16 + qi) * 512 + d0);
            const bf16* qp = (const bf16*)&qv;
            #pragma unroll
            for (int e = 0; e < 8; ++e) Qs[qi][d0 + e] = __bfloat162float(qp[e]) * 0.125f;
        }
        __syncthreads();

        int i = t >> 4;
        int j0 = (t & 15) * 8;

        // phase 1: S[i][j0..j0+7] = Q[i] . K[j]
        if (j0 < len) {
            float a[8];
            #pragma unroll
            for (int e = 0; e < 8; ++e) a[e] = 0.f;
            #pragma unroll 4
            for (int d = 0; d < 64; ++d) {
                float qv = Qs[i][d];
                const float4* kp = (const float4*)&Kt[d][j0];
                float4 k0v = kp[0];
                float4 k1v = kp[1];
                a[0] += qv * k0v.x; a[1] += qv * k0v.y;
                a[2] += qv * k0v.z; a[3] += qv * k0v.w;
                a[4] += qv * k1v.x; a[5] += qv * k1v.y;
                a[6] += qv * k1v.z; a[7] += qv * k1v.w;
            }
            #pragma unroll
            for (int e = 0; e < 8; ++e) S[i][j0 + e] = a[e];
        }
        __syncthreads();

        // softmax over row i (16 lanes per row, consecutive)
        {
            float vals[8];
            float mx = -1e30f;
            if (j0 < len) {
                #pragma unroll
                for (int e = 0; e < 8; ++e) { vals[e] = S[i][j0 + e]; mx = fmaxf(mx, vals[e]); }
            }
            #pragma unroll
            for (int mk = 1; mk < 16; mk <<= 1) mx = fmaxf(mx, __shfl_xor(mx, mk));
            float sum = 0.f;
            if (j0 < len) {
                #pragma unroll
                for (int e = 0; e < 8; ++e) { vals[e] = __expf(vals[e] - mx); sum += vals[e]; }
            }
            #pragma unroll
            for (int mk = 1; mk < 16; mk <<= 1) sum += __shfl_xor(sum, mk);
            float inv = 1.f / sum;
            if (j0 < len) {
                #pragma unroll
                for (int e = 0; e < 8; ++e) S[i][j0 + e] = vals[e] * inv;
            }
        }
        __syncthreads();

        // phase 3: O[i][d0..d0+3] = sum_j P[i][j] * V[j][d]
        {
            int d0 = (t & 15) * 4;
            float o0 = 0.f, o1 = 0.f, o2 = 0.f, o3 = 0.f;
            for (int j = 0; j < len; ++j) {
                float p = S[i][j];
                uint2 vv = *(const uint2*)&Vs[j][d0];
                const bf16* vp = (const bf16*)&vv;
                o0 += p * __bfloat162float(vp[0]);
                o1 += p * __bfloat162float(vp[1]);
                o2 += p * __bfloat162float(vp[2]);
                o3 += p * __bfloat162float(vp[3]);
            }
            bf16* orow = o + base + (size_t)(sl * 16 + i) * 512 + d0;
            orow[0] = __float2bfloat16(o0);
            orow[1] = __float2bfloat16(o1);
            orow[2] = __float2bfloat16(o2);
            orow[3] = __float2bfloat16(o3);
        }
    }
}

// ---------------------------------------------------------------- residual + layernorm (row = 512)
// writes bf16 (out_bf) or fp32 (out_f) depending on which pointer is non-null
__global__ __launch_bounds__(256) void ln_kernel(const bf16* x, const bf16* res,
                                                 const float* __restrict__ g,
                                                 const float* __restrict__ bta,
                                                 bf16* out_bf, float* out_f) {
    int row = blockIdx.x;
    int t = threadIdx.x;
    const bf16* xr = x + (size_t)row * 512;
    float v0 = __bfloat162float(xr[t]);
    float v1 = __bfloat162float(xr[t + 256]);
    if (res) {
        const bf16* rr = res + (size_t)row * 512;
        v0 += __bfloat162float(rr[t]);
        v1 += __bfloat162float(rr[t + 256]);
    }
    float s = v0 + v1, ss = v0 * v0 + v1 * v1;
    #pragma unroll
    for (int mk = 1; mk < 64; mk <<= 1) { s += __shfl_xor(s, mk); ss += __shfl_xor(ss, mk); }
    __shared__ float red[8];
    int wave = t >> 6, lane = t & 63;
    if (lane == 0) { red[wave * 2] = s; red[wave * 2 + 1] = ss; }
    __syncthreads();
    s = red[0] + red[2] + red[4] + red[6];
    ss = red[1] + red[3] + red[5] + red[7];
    float mu = s * (1.f / 512.f);
    float var = ss * (1.f / 512.f) - mu * mu;
    float inv = rsqrtf(var + 1e-5f);
    float y0 = (v0 - mu) * inv * g[t] + bta[t];
    float y1 = (v1 - mu) * inv * g[t + 256] + bta[t + 256];
    if (out_bf) {
        bf16* orow = out_bf + (size_t)row * 512;
        orow[t] = __float2bfloat16(y0);
        orow[t + 256] = __float2bfloat16(y1);
    } else {
        float* orow = out_f + (size_t)row * 512;
        orow[t] = y0;
        orow[t + 256] = y1;
    }
}

// ---------------------------------------------------------------- launch
extern "C" void kernel_launch(void* const* d_in, const int* in_sizes, int n_in,
                              void* d_out, int out_size, void* d_ws, size_t ws_size,
                              hipStream_t stream) {
    const float* x_enc = (const float*)d_in[0];
    const float* W_emb = (const float*)d_in[1];
    const float* Wq    = (const float*)d_in[2];
    const float* bq    = (const float*)d_in[3];
    const float* Wk    = (const float*)d_in[4];
    const float* bk    = (const float*)d_in[5];
    const float* Wv    = (const float*)d_in[6];
    const float* bv    = (const float*)d_in[7];
    const float* Wo    = (const float*)d_in[8];
    const float* bo    = (const float*)d_in[9];
    const float* ln1_g = (const float*)d_in[10];
    const float* ln1_b = (const float*)d_in[11];
    const float* W1    = (const float*)d_in[12];
    const float* b1    = (const float*)d_in[13];
    const float* W2    = (const float*)d_in[14];
    const float* b2    = (const float*)d_in[15];
    const float* ln2_g = (const float*)d_in[16];
    const float* ln2_b = (const float*)d_in[17];
    const float* lnf_g = (const float*)d_in[18];
    const float* lnf_b = (const float*)d_in[19];

    const int ROWS = 256 * 240;            // 61440
    char* ws = (char*)d_ws;
    const size_t Hb = (size_t)ROWS * 512 * 2;  // 62,914,560 B
    bf16* h   = (bf16*)(ws);
    bf16* qb  = (bf16*)(ws + Hb);
    bf16* kb  = (bf16*)(ws + 2 * Hb);
    bf16* vb  = (bf16*)(ws + 3 * Hb);
    bf16* oa  = (bf16*)(ws + 4 * Hb);
    bf16* tmp = (bf16*)(ws + 5 * Hb);
    bf16* mid = qb;                        // aliases q..oa (4*Hb = 61440*2048*2)
    bf16* WqT = (bf16*)(ws + 6 * Hb);
    bf16* WkT = WqT + (size_t)3 * 512 * 512;
    bf16* WvT = WkT + (size_t)3 * 512 * 512;
    bf16* WoT = WvT + (size_t)3 * 512 * 512;
    bf16* W1T = WoT + (size_t)3 * 512 * 512;
    bf16* W2T = W1T + (size_t)3 * 512 * 2048;

    dim3 blk(256);
    transpose_f32_bf16<<<dim3(16, 16, 3), blk, 0, stream>>>(Wq, WqT, 512, 512);
    transpose_f32_bf16<<<dim3(16, 16, 3), blk, 0, stream>>>(Wk, WkT, 512, 512);
    transpose_f32_bf16<<<dim3(16, 16, 3), blk, 0, stream>>>(Wv, WvT, 512, 512);
    transpose_f32_bf16<<<dim3(16, 16, 3), blk, 0, stream>>>(Wo, WoT, 512, 512);
    transpose_f32_bf16<<<dim3(64, 16, 3), blk, 0, stream>>>(W1, W1T, 512, 2048);
    transpose_f32_bf16<<<dim3(16, 64, 3), blk, 0, stream>>>(W2, W2T, 2048, 512);

    embed_kernel<<<ROWS, blk, 0, stream>>>(x_enc, W_emb, h);

    for (int L = 0; L < 3; ++L) {
        size_t wo = (size_t)L * 512 * 512;
        size_t w1o = (size_t)L * 512 * 2048;
        gemm_bt<<<dim3(4, 480), blk, 0, stream>>>(h, WqT + wo, bq + L * 512, qb, ROWS, 512, 512, 0);
        gemm_bt<<<dim3(4, 480), blk, 0, stream>>>(h, WkT + wo, bk + L * 512, kb, ROWS, 512, 512, 0);
        gemm_bt<<<dim3(4, 480), blk, 0, stream>>>(h, WvT + wo, bv + L * 512, vb, ROWS, 512, 512, 0);
        attn_kernel<<<8192, blk, 0, stream>>>(qb, kb, vb, oa);
        gemm_bt<<<dim3(4, 480), blk, 0, stream>>>(oa, WoT + wo, bo + L * 512, tmp, ROWS, 512, 512, 0);
        ln_kernel<<<ROWS, blk, 0, stream>>>(h, tmp, ln1_g + L * 512, ln1_b + L * 512, h, nullptr);
        gemm_bt<<<dim3(16, 480), blk, 0, stream>>>(h, W1T + w1o, b1 + L * 2048, mid, ROWS, 2048, 512, 1);
        gemm_bt<<<dim3(4, 480), blk, 0, stream>>>(mid, W2T + w1o, b2 + L * 512, tmp, ROWS, 512, 2048, 0);
        ln_kernel<<<ROWS, blk, 0, stream>>>(h, tmp, ln2_g + L * 512, ln2_b + L * 512, h, nullptr);
    }
    ln_kernel<<<ROWS, blk, 0, stream>>>(h, nullptr, lnf_g, lnf_b, nullptr, (float*)d_out);
}

// Round 3
// 3432.815 us; speedup vs baseline: 1.7472x; 1.7472x over previous
//
#include <hip/hip_runtime.h>
#include <hip/hip_bf16.h>

typedef short bf16x8 __attribute__((ext_vector_type(8)));
typedef float f32x4 __attribute__((ext_vector_type(4)));
using bf16 = __hip_bfloat16;

// ---------------------------------------------------------------- utilities
static __device__ __forceinline__ float gelu_f(float x) {
    float x3 = x * x * x;
    return 0.5f * x * (1.0f + tanhf(0.7978845608028654f * (x + 0.044715f * x3)));
}

// ---------------------------------------------------------------- transpose + downcast (f32 -> bf16), batched over z
__global__ __launch_bounds__(256) void transpose_f32_bf16(const float* __restrict__ in,
                                                          bf16* __restrict__ out,
                                                          int R, int C) {
    __shared__ float tile[32][33];
    size_t zo = (size_t)blockIdx.z * R * C;
    int c0 = blockIdx.x * 32, r0 = blockIdx.y * 32;
    int tx = threadIdx.x & 31, ty = threadIdx.x >> 5;
    #pragma unroll
    for (int i = 0; i < 32; i += 8) {
        int r = r0 + ty + i, c = c0 + tx;
        if (r < R && c < C) tile[ty + i][tx] = in[zo + (size_t)r * C + c];
    }
    __syncthreads();
    #pragma unroll
    for (int i = 0; i < 32; i += 8) {
        int c = c0 + ty + i, r = r0 + tx;
        if (c < C && r < R) out[zo + (size_t)c * R + r] = __float2bfloat16(tile[tx][ty + i]);
    }
}

// ---------------------------------------------------------------- V transpose per batch-row: vb[b*240+t][512] -> vt[b*512+d][240]
__global__ __launch_bounds__(256) void transpose_v(const bf16* __restrict__ in,
                                                   bf16* __restrict__ out) {
    __shared__ bf16 tile[32][33];
    int b = blockIdx.z;
    int d0 = blockIdx.x * 32, t0 = blockIdx.y * 32;
    int tx = threadIdx.x & 31, ty = threadIdx.x >> 5;
    #pragma unroll
    for (int i = 0; i < 32; i += 8) {
        int tt = t0 + ty + i, dd = d0 + tx;
        if (tt < 240) tile[ty + i][tx] = in[((size_t)b * 240 + tt) * 512 + dd];
    }
    __syncthreads();
    #pragma unroll
    for (int i = 0; i < 32; i += 8) {
        int dd = d0 + ty + i, tt = t0 + tx;
        if (tt < 240) out[((size_t)b * 512 + dd) * 240 + tt] = tile[tx][ty + i];
    }
}

// ---------------------------------------------------------------- patch embedding + positional encoding
__global__ __launch_bounds__(256) void embed_kernel(const float* __restrict__ x_enc,
                                                    const float* __restrict__ W_emb, // [16][512]
                                                    bf16* __restrict__ h) {
    int row = blockIdx.x;
    int b = row / 240, l = row - b * 240;
    int s = (l < 16) ? 0 : (l < 48) ? 1 : (l < 112) ? 2 : 3;
    int len = 16 << s;
    int off = len - 16;           // 0,16,48,112
    int kk = 8 >> s;              // 8,4,2,1
    int j = l - off;
    int bs_i = b >> 5, c_i = b & 31;
    __shared__ float xv[16];
    int t = threadIdx.x;
    if (t < 16) {
        int tau = (j * 16 + t) * kk;
        xv[t] = x_enc[((size_t)bs_i * 2048 + tau) * 32 + c_i];
    }
    __syncthreads();
    int pe_row = j * kk;
    const float NEG2LN = -0.035977892078032f; // -2*ln(10000)/512
    for (int d = t; d < 512; d += 256) {
        float acc = 0.f;
        #pragma unroll
        for (int i = 0; i < 16; ++i) acc += xv[i] * W_emb[i * 512 + d];
        int di = d >> 1;
        float ang = (float)pe_row * expf((float)di * NEG2LN);
        float pos = (d & 1) ? cosf(ang) : sinf(ang);
        h[(size_t)row * 512 + d] = __float2bfloat16(acc + pos);
    }
}

// ---------------------------------------------------------------- GEMM: C[M,N] = A[M,K] @ Bt[N,K]^T + bias (+gelu)
#define GBM 128
#define GBN 128
#define GBK 32
#define GLDA 56   // padded LDS stride (112 B = odd multiple of 16 B -> conflict-free b128)

__global__ __launch_bounds__(256) void gemm_bt(const bf16* __restrict__ A,
                                               const bf16* __restrict__ Bt,
                                               const float* __restrict__ bias,
                                               bf16* __restrict__ C,
                                               int M, int N, int K, int act) {
    __shared__ bf16 As[GBM * GLDA];
    __shared__ bf16 Bs[GBN * GLDA];
    const int t = threadIdx.x;
    const int wave = t >> 6, lane = t & 63;
    const int quad = lane >> 4, l16 = lane & 15;
    const int m0 = blockIdx.y * GBM, n0 = blockIdx.x * GBN;
    const int wm = (wave >> 1) * 64, wn = (wave & 1) * 64;

    f32x4 acc[4][4];
    #pragma unroll
    for (int a = 0; a < 4; ++a)
        #pragma unroll
        for (int b = 0; b < 4; ++b)
            #pragma unroll
            for (int r = 0; r < 4; ++r) acc[a][b][r] = 0.0f;

    const int lrow = t >> 2;        // 0..63
    const int lkc = (t & 3) * 8;    // 0,8,16,24

    for (int k0 = 0; k0 < K; k0 += GBK) {
        __syncthreads();
        #pragma unroll
        for (int p = 0; p < 2; ++p) {
            int r = lrow + p * 64;
            *(uint4*)(&As[r * GLDA + lkc]) =
                *(const uint4*)(A + (size_t)(m0 + r) * K + k0 + lkc);
            *(uint4*)(&Bs[r * GLDA + lkc]) =
                *(const uint4*)(Bt + (size_t)(n0 + r) * K + k0 + lkc);
        }
        __syncthreads();
        bf16x8 af[4], bfr[4];
        #pragma unroll
        for (int mi = 0; mi < 4; ++mi)
            af[mi] = *(const bf16x8*)(&As[(wm + mi * 16 + l16) * GLDA + quad * 8]);
        #pragma unroll
        for (int ni = 0; ni < 4; ++ni)
            bfr[ni] = *(const bf16x8*)(&Bs[(wn + ni * 16 + l16) * GLDA + quad * 8]);
        #pragma unroll
        for (int mi = 0; mi < 4; ++mi)
            #pragma unroll
            for (int ni = 0; ni < 4; ++ni)
                acc[mi][ni] = __builtin_amdgcn_mfma_f32_16x16x32_bf16(af[mi], bfr[ni],
                                                                     acc[mi][ni], 0, 0, 0);
    }

    #pragma unroll
    for (int ni = 0; ni < 4; ++ni) {
        int col = n0 + wn + ni * 16 + l16;
        float bv = bias[col];
        #pragma unroll
        for (int mi = 0; mi < 4; ++mi) {
            #pragma unroll
            for (int r = 0; r < 4; ++r) {
                int row = m0 + wm + mi * 16 + quad * 4 + r;
                float x = acc[mi][ni][r] + bv;
                if (act) x = gelu_f(x);
                C[(size_t)row * N + col] = __float2bfloat16(x);
            }
        }
    }
}

// ---------------------------------------------------------------- MFMA segment attention
// One wave per (b, head, 16-row q-slab); templated on segment length.
// Q/K frags: direct global uint4 loads (A/B operand layouts are 16B/lane contiguous).
// V frags: direct loads from pre-transposed vt[b][d][240].
// P: C/D->A layout round-trip through per-wave LDS (bf16).
template<int LEN>
__global__ __launch_bounds__(256) void attn_mfma(const bf16* __restrict__ q,
                                                 const bf16* __restrict__ k,
                                                 const bf16* __restrict__ vt,
                                                 bf16* __restrict__ o) {
    constexpr int NT = LEN / 16;                    // score col tiles
    constexpr int KT = (LEN >= 32) ? (LEN / 32) : 1; // PV k tiles (len=16 zero-padded)
    constexpr int PST = (LEN == 16) ? 40 : (LEN + 8); // P row stride (elements)
    constexpr int SLABS = LEN / 16;
    constexpr int OFF = LEN - 16;
    __shared__ __align__(16) bf16 Plds[4 * 16 * PST];

    const int t = threadIdx.x;
    const int wave = t >> 6, lane = t & 63;
    const int quad = lane >> 4, l16 = lane & 15;
    const int task = blockIdx.x * 4 + wave;
    const int b = task / (8 * SLABS);
    const int rem = task - b * (8 * SLABS);
    const int h = rem / SLABS;
    const int slab = rem - h * SLABS;

    const size_t base = ((size_t)b * 240 + OFF) * 512 + h * 64;

    const bf16* qp = q + base + (size_t)(slab * 16 + l16) * 512 + quad * 8;
    bf16x8 qf0 = *(const bf16x8*)qp;
    bf16x8 qf1 = *(const bf16x8*)(qp + 32);

    f32x4 sacc[NT];
    #pragma unroll
    for (int nt = 0; nt < NT; ++nt) {
        const bf16* kp = k + base + (size_t)(nt * 16 + l16) * 512 + quad * 8;
        bf16x8 kf0 = *(const bf16x8*)kp;
        bf16x8 kf1 = *(const bf16x8*)(kp + 32);
        f32x4 a = {0.f, 0.f, 0.f, 0.f};
        a = __builtin_amdgcn_mfma_f32_16x16x32_bf16(qf0, kf0, a, 0, 0, 0);
        a = __builtin_amdgcn_mfma_f32_16x16x32_bf16(qf1, kf1, a, 0, 0, 0);
        sacc[nt] = a;
    }

    // softmax over rows i = quad*4+r; cols spread over (nt, l16)
    float mx[4], sm[4];
    #pragma unroll
    for (int r = 0; r < 4; ++r) mx[r] = -3.0e38f;
    #pragma unroll
    for (int nt = 0; nt < NT; ++nt)
        #pragma unroll
        for (int r = 0; r < 4; ++r) {
            sacc[nt][r] *= 0.125f;          // 1/sqrt(64)
            mx[r] = fmaxf(mx[r], sacc[nt][r]);
        }
    #pragma unroll
    for (int msk = 1; msk < 16; msk <<= 1)
        #pragma unroll
        for (int r = 0; r < 4; ++r) mx[r] = fmaxf(mx[r], __shfl_xor(mx[r], msk));
    #pragma unroll
    for (int r = 0; r < 4; ++r) sm[r] = 0.f;
    #pragma unroll
    for (int nt = 0; nt < NT; ++nt)
        #pragma unroll
        for (int r = 0; r < 4; ++r) {
            float p = __expf(sacc[nt][r] - mx[r]);
            sacc[nt][r] = p;
            sm[r] += p;
        }
    #pragma unroll
    for (int msk = 1; msk < 16; msk <<= 1)
        #pragma unroll
        for (int r = 0; r < 4; ++r) sm[r] += __shfl_xor(sm[r], msk);
    float inv[4];
    #pragma unroll
    for (int r = 0; r < 4; ++r) inv[r] = 1.f / sm[r];

    // P: C/D layout -> LDS -> A layout
    bf16* pw = Plds + wave * 16 * PST;
    #pragma unroll
    for (int nt = 0; nt < NT; ++nt)
        #pragma unroll
        for (int r = 0; r < 4; ++r)
            pw[(quad * 4 + r) * PST + nt * 16 + l16] =
                __float2bfloat16(sacc[nt][r] * inv[r]);
    if (LEN == 16) {
        #pragma unroll
        for (int r = 0; r < 4; ++r)
            pw[(quad * 4 + r) * PST + 16 + l16] = __float2bfloat16(0.f);
    }
    __syncthreads();

    f32x4 oacc[4];
    #pragma unroll
    for (int n4 = 0; n4 < 4; ++n4) {
        f32x4 z = {0.f, 0.f, 0.f, 0.f};
        oacc[n4] = z;
    }
    #pragma unroll
    for (int kt = 0; kt < KT; ++kt) {
        bf16x8 pf = *(const bf16x8*)&pw[l16 * PST + kt * 32 + quad * 8];
        #pragma unroll
        for (int n4 = 0; n4 < 4; ++n4) {
            const bf16* vp = vt + ((size_t)b * 512 + h * 64 + n4 * 16 + l16) * 240
                              + OFF + kt * 32 + quad * 8;
            bf16x8 vf = *(const bf16x8*)vp;
            oacc[n4] = __builtin_amdgcn_mfma_f32_16x16x32_bf16(pf, vf, oacc[n4], 0, 0, 0);
        }
    }
    #pragma unroll
    for (int n4 = 0; n4 < 4; ++n4)
        #pragma unroll
        for (int r = 0; r < 4; ++r)
            o[base + (size_t)(slab * 16 + quad * 4 + r) * 512 + n4 * 16 + l16] =
                __float2bfloat16(oacc[n4][r]);
}

// ---------------------------------------------------------------- residual + layernorm (row = 512)
__global__ __launch_bounds__(256) void ln_kernel(const bf16* x, const bf16* res,
                                                 const float* __restrict__ g,
                                                 const float* __restrict__ bta,
                                                 bf16* out_bf, float* out_f) {
    int row = blockIdx.x;
    int t = threadIdx.x;
    const bf16* xr = x + (size_t)row * 512;
    float v0 = __bfloat162float(xr[t]);
    float v1 = __bfloat162float(xr[t + 256]);
    if (res) {
        const bf16* rr = res + (size_t)row * 512;
        v0 += __bfloat162float(rr[t]);
        v1 += __bfloat162float(rr[t + 256]);
    }
    float s = v0 + v1, ss = v0 * v0 + v1 * v1;
    #pragma unroll
    for (int mk = 1; mk < 64; mk <<= 1) { s += __shfl_xor(s, mk); ss += __shfl_xor(ss, mk); }
    __shared__ float red[8];
    int wave = t >> 6, lane = t & 63;
    if (lane == 0) { red[wave * 2] = s; red[wave * 2 + 1] = ss; }
    __syncthreads();
    s = red[0] + red[2] + red[4] + red[6];
    ss = red[1] + red[3] + red[5] + red[7];
    float mu = s * (1.f / 512.f);
    float var = ss * (1.f / 512.f) - mu * mu;
    float inv = rsqrtf(var + 1e-5f);
    float y0 = (v0 - mu) * inv * g[t] + bta[t];
    float y1 = (v1 - mu) * inv * g[t + 256] + bta[t + 256];
    if (out_bf) {
        bf16* orow = out_bf + (size_t)row * 512;
        orow[t] = __float2bfloat16(y0);
        orow[t + 256] = __float2bfloat16(y1);
    } else {
        float* orow = out_f + (size_t)row * 512;
        orow[t] = y0;
        orow[t + 256] = y1;
    }
}

// ---------------------------------------------------------------- launch
extern "C" void kernel_launch(void* const* d_in, const int* in_sizes, int n_in,
                              void* d_out, int out_size, void* d_ws, size_t ws_size,
                              hipStream_t stream) {
    const float* x_enc = (const float*)d_in[0];
    const float* W_emb = (const float*)d_in[1];
    const float* Wq    = (const float*)d_in[2];
    const float* bq    = (const float*)d_in[3];
    const float* Wk    = (const float*)d_in[4];
    const float* bk    = (const float*)d_in[5];
    const float* Wv    = (const float*)d_in[6];
    const float* bv    = (const float*)d_in[7];
    const float* Wo    = (const float*)d_in[8];
    const float* bo    = (const float*)d_in[9];
    const float* ln1_g = (const float*)d_in[10];
    const float* ln1_b = (const float*)d_in[11];
    const float* W1    = (const float*)d_in[12];
    const float* b1    = (const float*)d_in[13];
    const float* W2    = (const float*)d_in[14];
    const float* b2    = (const float*)d_in[15];
    const float* ln2_g = (const float*)d_in[16];
    const float* ln2_b = (const float*)d_in[17];
    const float* lnf_g = (const float*)d_in[18];
    const float* lnf_b = (const float*)d_in[19];

    const int ROWS = 256 * 240;            // 61440
    char* ws = (char*)d_ws;
    const size_t Hb = (size_t)ROWS * 512 * 2;  // 62,914,560 B
    bf16* h   = (bf16*)(ws);
    bf16* qb  = (bf16*)(ws + Hb);
    bf16* kb  = (bf16*)(ws + 2 * Hb);
    bf16* vb  = (bf16*)(ws + 3 * Hb);
    bf16* oa  = (bf16*)(ws + 4 * Hb);
    bf16* vt  = (bf16*)(ws + 5 * Hb);      // V transposed [b][512][240]; dead after attn
    bf16* oproj = vb;                      // o-projection output (vb dead after transpose_v)
    bf16* ffnout = vt;                     // FFN2 output (vt dead after attn)
    bf16* mid = qb;                        // FFN mid aliases qb..oa (4*Hb)
    bf16* WqT = (bf16*)(ws + 6 * Hb);
    bf16* WkT = WqT + (size_t)3 * 512 * 512;
    bf16* WvT = WkT + (size_t)3 * 512 * 512;
    bf16* WoT = WvT + (size_t)3 * 512 * 512;
    bf16* W1T = WoT + (size_t)3 * 512 * 512;
    bf16* W2T = W1T + (size_t)3 * 512 * 2048;

    dim3 blk(256);
    transpose_f32_bf16<<<dim3(16, 16, 3), blk, 0, stream>>>(Wq, WqT, 512, 512);
    transpose_f32_bf16<<<dim3(16, 16, 3), blk, 0, stream>>>(Wk, WkT, 512, 512);
    transpose_f32_bf16<<<dim3(16, 16, 3), blk, 0, stream>>>(Wv, WvT, 512, 512);
    transpose_f32_bf16<<<dim3(16, 16, 3), blk, 0, stream>>>(Wo, WoT, 512, 512);
    transpose_f32_bf16<<<dim3(64, 16, 3), blk, 0, stream>>>(W1, W1T, 512, 2048);
    transpose_f32_bf16<<<dim3(16, 64, 3), blk, 0, stream>>>(W2, W2T, 2048, 512);

    embed_kernel<<<ROWS, blk, 0, stream>>>(x_enc, W_emb, h);

    for (int L = 0; L < 3; ++L) {
        size_t wo = (size_t)L * 512 * 512;
        size_t w1o = (size_t)L * 512 * 2048;
        gemm_bt<<<dim3(4, 480), blk, 0, stream>>>(h, WqT + wo, bq + L * 512, qb, ROWS, 512, 512, 0);
        gemm_bt<<<dim3(4, 480), blk, 0, stream>>>(h, WkT + wo, bk + L * 512, kb, ROWS, 512, 512, 0);
        gemm_bt<<<dim3(4, 480), blk, 0, stream>>>(h, WvT + wo, bv + L * 512, vb, ROWS, 512, 512, 0);
        transpose_v<<<dim3(16, 8, 256), blk, 0, stream>>>(vb, vt);
        attn_mfma<16><<<512, blk, 0, stream>>>(qb, kb, vt, oa);
        attn_mfma<32><<<1024, blk, 0, stream>>>(qb, kb, vt, oa);
        attn_mfma<64><<<2048, blk, 0, stream>>>(qb, kb, vt, oa);
        attn_mfma<128><<<4096, blk, 0, stream>>>(qb, kb, vt, oa);
        gemm_bt<<<dim3(4, 480), blk, 0, stream>>>(oa, WoT + wo, bo + L * 512, oproj, ROWS, 512, 512, 0);
        ln_kernel<<<ROWS, blk, 0, stream>>>(h, oproj, ln1_g + L * 512, ln1_b + L * 512, h, nullptr);
        gemm_bt<<<dim3(16, 480), blk, 0, stream>>>(h, W1T + w1o, b1 + L * 2048, mid, ROWS, 2048, 512, 1);
        gemm_bt<<<dim3(4, 480), blk, 0, stream>>>(mid, W2T + w1o, b2 + L * 512, ffnout, ROWS, 512, 2048, 0);
        ln_kernel<<<ROWS, blk, 0, stream>>>(h, ffnout, ln2_g + L * 512, ln2_b + L * 512, h, nullptr);
    }
    ln_kernel<<<ROWS, blk, 0, stream>>>(h, nullptr, lnf_g, lnf_b, nullptr, (float*)d_out);
}

// Round 4
// 3200.652 us; speedup vs baseline: 1.8739x; 1.0725x over previous
//
#include <hip/hip_runtime.h>
#include <hip/hip_bf16.h>

typedef short bf16x8 __attribute__((ext_vector_type(8)));
typedef float f32x4 __attribute__((ext_vector_type(4)));
using bf16 = __hip_bfloat16;

#define GLOBAL_LOAD_LDS16(g, l)                                                          \
    __builtin_amdgcn_global_load_lds((const __attribute__((address_space(1))) unsigned int*)(g), \
                                     (__attribute__((address_space(3))) unsigned int*)(l), \
                                     16, 0, 0)

// ---------------------------------------------------------------- utilities
// gelu(x) = 0.5x(1+tanh(0.79788456x(1+0.044715x^2))) = x * sigmoid(1.5957691x(1+0.044715x^2))
static __device__ __forceinline__ float gelu_f(float x) {
    float u = 1.5957691216057308f * x * (1.0f + 0.044715f * x * x);
    return x / (1.0f + __expf(-u));
}

// ---------------------------------------------------------------- transpose + downcast (f32 -> bf16), batched over z
// out z-stride is a parameter so q/k/v transposes can interleave into one [L][1536][512] buffer
__global__ __launch_bounds__(256) void transpose_f32_bf16(const float* __restrict__ in,
                                                          bf16* __restrict__ out,
                                                          int R, int C, size_t zso) {
    __shared__ float tile[32][33];
    size_t zi = (size_t)blockIdx.z * R * C;
    size_t zo = (size_t)blockIdx.z * zso;
    int c0 = blockIdx.x * 32, r0 = blockIdx.y * 32;
    int tx = threadIdx.x & 31, ty = threadIdx.x >> 5;
    #pragma unroll
    for (int i = 0; i < 32; i += 8) {
        int r = r0 + ty + i, c = c0 + tx;
        if (r < R && c < C) tile[ty + i][tx] = in[zi + (size_t)r * C + c];
    }
    __syncthreads();
    #pragma unroll
    for (int i = 0; i < 32; i += 8) {
        int c = c0 + ty + i, r = r0 + tx;
        if (c < C && r < R) out[zo + (size_t)c * R + r] = __float2bfloat16(tile[tx][ty + i]);
    }
}

// ---------------------------------------------------------------- bias concat: [L][1536] = bq|bk|bv
__global__ __launch_bounds__(256) void concat_bias(const float* __restrict__ bq,
                                                   const float* __restrict__ bk,
                                                   const float* __restrict__ bv,
                                                   float* __restrict__ out) {
    int i = blockIdx.x * 256 + threadIdx.x;
    if (i < 3 * 1536) {
        int L = i / 1536, r = i - L * 1536;
        float v = (r < 512) ? bq[L * 512 + r]
                : (r < 1024) ? bk[L * 512 + r - 512]
                             : bv[L * 512 + r - 1024];
        out[i] = v;
    }
}

// ---------------------------------------------------------------- V transpose: qkv[b*240+t][1536] (cols 1024..1535) -> vt[b*512+d][240]
__global__ __launch_bounds__(256) void transpose_v(const bf16* __restrict__ in,
                                                   bf16* __restrict__ out) {
    __shared__ bf16 tile[32][33];
    int b = blockIdx.z;
    int d0 = blockIdx.x * 32, t0 = blockIdx.y * 32;
    int tx = threadIdx.x & 31, ty = threadIdx.x >> 5;
    #pragma unroll
    for (int i = 0; i < 32; i += 8) {
        int tt = t0 + ty + i, dd = d0 + tx;
        if (tt < 240) tile[ty + i][tx] = in[((size_t)b * 240 + tt) * 1536 + 1024 + dd];
    }
    __syncthreads();
    #pragma unroll
    for (int i = 0; i < 32; i += 8) {
        int dd = d0 + ty + i, tt = t0 + tx;
        if (tt < 240) out[((size_t)b * 512 + dd) * 240 + tt] = tile[tx][ty + i];
    }
}

// ---------------------------------------------------------------- patch embedding + positional encoding
__global__ __launch_bounds__(256) void embed_kernel(const float* __restrict__ x_enc,
                                                    const float* __restrict__ W_emb, // [16][512]
                                                    bf16* __restrict__ h) {
    int row = blockIdx.x;
    int b = row / 240, l = row - b * 240;
    int s = (l < 16) ? 0 : (l < 48) ? 1 : (l < 112) ? 2 : 3;
    int len = 16 << s;
    int off = len - 16;           // 0,16,48,112
    int kk = 8 >> s;              // 8,4,2,1
    int j = l - off;
    int bs_i = b >> 5, c_i = b & 31;
    __shared__ float xv[16];
    int t = threadIdx.x;
    if (t < 16) {
        int tau = (j * 16 + t) * kk;
        xv[t] = x_enc[((size_t)bs_i * 2048 + tau) * 32 + c_i];
    }
    __syncthreads();
    int pe_row = j * kk;
    const float NEG2LN = -0.035977892078032f; // -2*ln(10000)/512
    for (int d = t; d < 512; d += 256) {
        float acc = 0.f;
        #pragma unroll
        for (int i = 0; i < 16; ++i) acc += xv[i] * W_emb[i * 512 + d];
        int di = d >> 1;
        float ang = (float)pe_row * expf((float)di * NEG2LN);
        float pos = (d & 1) ? cosf(ang) : sinf(ang);
        h[(size_t)row * 512 + d] = __float2bfloat16(acc + pos);
    }
}

// ---------------------------------------------------------------- GEMM: C[M,N] = A[M,K] @ Bt[N,K]^T + bias (+gelu)
// 128x128 tile, BK=32, global_load_lds width-16 staging, XOR-swizzled LDS chunks.
__global__ __launch_bounds__(256) void gemm_bt(const bf16* __restrict__ A,
                                               const bf16* __restrict__ Bt,
                                               const float* __restrict__ bias,
                                               bf16* __restrict__ C,
                                               int M, int N, int K, int act) {
    __shared__ __align__(16) bf16 As[128 * 32];
    __shared__ __align__(16) bf16 Bs[128 * 32];
    const int t = threadIdx.x;
    const int wave = t >> 6, lane = t & 63;
    const int quad = lane >> 4, l16 = lane & 15;
    const int m0 = blockIdx.y * 128, n0 = blockIdx.x * 128;
    const int wm = (wave >> 1) * 64, wn = (wave & 1) * 64;

    f32x4 acc[4][4];
    #pragma unroll
    for (int a = 0; a < 4; ++a)
        #pragma unroll
        for (int b = 0; b < 4; ++b)
            #pragma unroll
            for (int r = 0; r < 4; ++r) acc[a][b][r] = 0.0f;

    const int lr = lane >> 2;              // row within 16-row group
    const int lc = lane & 3;               // chunk slot (16 B)
    const int csw = lc ^ (lr & 3);         // swizzled source chunk
    const int fsw = quad ^ (l16 & 3);      // swizzled fragment chunk

    for (int k0 = 0; k0 < K; k0 += 32) {
        __syncthreads();
        #pragma unroll
        for (int p = 0; p < 2; ++p) {
            int g = p * 4 + wave;          // 16-row group 0..7
            int row = g * 16 + lr;
            const bf16* ga = A + (size_t)(m0 + row) * K + k0 + csw * 8;
            const bf16* gb = Bt + (size_t)(n0 + row) * K + k0 + csw * 8;
            GLOBAL_LOAD_LDS16(ga, As + g * 512);
            GLOBAL_LOAD_LDS16(gb, Bs + g * 512);
        }
        __syncthreads();
        bf16x8 af[4], bfr[4];
        #pragma unroll
        for (int mi = 0; mi < 4; ++mi)
            af[mi] = *(const bf16x8*)(&As[(wm + mi * 16 + l16) * 32 + fsw * 8]);
        #pragma unroll
        for (int ni = 0; ni < 4; ++ni)
            bfr[ni] = *(const bf16x8*)(&Bs[(wn + ni * 16 + l16) * 32 + fsw * 8]);
        #pragma unroll
        for (int mi = 0; mi < 4; ++mi)
            #pragma unroll
            for (int ni = 0; ni < 4; ++ni)
                acc[mi][ni] = __builtin_amdgcn_mfma_f32_16x16x32_bf16(af[mi], bfr[ni],
                                                                     acc[mi][ni], 0, 0, 0);
    }

    #pragma unroll
    for (int ni = 0; ni < 4; ++ni) {
        int col = n0 + wn + ni * 16 + l16;
        float bv = bias[col];
        #pragma unroll
        for (int mi = 0; mi < 4; ++mi) {
            #pragma unroll
            for (int r = 0; r < 4; ++r) {
                int row = m0 + wm + mi * 16 + quad * 4 + r;
                float x = acc[mi][ni][r] + bv;
                if (act) x = gelu_f(x);
                C[(size_t)row * N + col] = __float2bfloat16(x);
            }
        }
    }
}

// ---------------------------------------------------------------- MFMA segment attention (qkv fused input, stride 1536)
template<int LEN>
__global__ __launch_bounds__(256) void attn_mfma(const bf16* __restrict__ qkv,
                                                 const bf16* __restrict__ vt,
                                                 bf16* __restrict__ o) {
    constexpr int NT = LEN / 16;
    constexpr int KT = (LEN >= 32) ? (LEN / 32) : 1;
    constexpr int PST = (LEN == 16) ? 40 : (LEN + 8);
    constexpr int SLABS = LEN / 16;
    constexpr int OFF = LEN - 16;
    __shared__ __align__(16) bf16 Plds[4 * 16 * PST];

    const int t = threadIdx.x;
    const int wave = t >> 6, lane = t & 63;
    const int quad = lane >> 4, l16 = lane & 15;
    const int task = blockIdx.x * 4 + wave;
    const int b = task / (8 * SLABS);
    const int rem = task - b * (8 * SLABS);
    const int h = rem / SLABS;
    const int slab = rem - h * SLABS;

    const size_t qbase = ((size_t)b * 240 + OFF) * 1536 + h * 64;
    const size_t obase = ((size_t)b * 240 + OFF) * 512 + h * 64;

    const bf16* qp = qkv + qbase + (size_t)(slab * 16 + l16) * 1536 + quad * 8;
    bf16x8 qf0 = *(const bf16x8*)qp;
    bf16x8 qf1 = *(const bf16x8*)(qp + 32);

    f32x4 sacc[NT];
    #pragma unroll
    for (int nt = 0; nt < NT; ++nt) {
        const bf16* kp = qkv + qbase + 512 + (size_t)(nt * 16 + l16) * 1536 + quad * 8;
        bf16x8 kf0 = *(const bf16x8*)kp;
        bf16x8 kf1 = *(const bf16x8*)(kp + 32);
        f32x4 a = {0.f, 0.f, 0.f, 0.f};
        a = __builtin_amdgcn_mfma_f32_16x16x32_bf16(qf0, kf0, a, 0, 0, 0);
        a = __builtin_amdgcn_mfma_f32_16x16x32_bf16(qf1, kf1, a, 0, 0, 0);
        sacc[nt] = a;
    }

    float mx[4], sm[4];
    #pragma unroll
    for (int r = 0; r < 4; ++r) mx[r] = -3.0e38f;
    #pragma unroll
    for (int nt = 0; nt < NT; ++nt)
        #pragma unroll
        for (int r = 0; r < 4; ++r) {
            sacc[nt][r] *= 0.125f;
            mx[r] = fmaxf(mx[r], sacc[nt][r]);
        }
    #pragma unroll
    for (int msk = 1; msk < 16; msk <<= 1)
        #pragma unroll
        for (int r = 0; r < 4; ++r) mx[r] = fmaxf(mx[r], __shfl_xor(mx[r], msk));
    #pragma unroll
    for (int r = 0; r < 4; ++r) sm[r] = 0.f;
    #pragma unroll
    for (int nt = 0; nt < NT; ++nt)
        #pragma unroll
        for (int r = 0; r < 4; ++r) {
            float p = __expf(sacc[nt][r] - mx[r]);
            sacc[nt][r] = p;
            sm[r] += p;
        }
    #pragma unroll
    for (int msk = 1; msk < 16; msk <<= 1)
        #pragma unroll
        for (int r = 0; r < 4; ++r) sm[r] += __shfl_xor(sm[r], msk);
    float inv[4];
    #pragma unroll
    for (int r = 0; r < 4; ++r) inv[r] = 1.f / sm[r];

    bf16* pw = Plds + wave * 16 * PST;
    #pragma unroll
    for (int nt = 0; nt < NT; ++nt)
        #pragma unroll
        for (int r = 0; r < 4; ++r)
            pw[(quad * 4 + r) * PST + nt * 16 + l16] =
                __float2bfloat16(sacc[nt][r] * inv[r]);
    if (LEN == 16) {
        #pragma unroll
        for (int r = 0; r < 4; ++r)
            pw[(quad * 4 + r) * PST + 16 + l16] = __float2bfloat16(0.f);
    }
    __syncthreads();

    f32x4 oacc[4];
    #pragma unroll
    for (int n4 = 0; n4 < 4; ++n4) {
        f32x4 z = {0.f, 0.f, 0.f, 0.f};
        oacc[n4] = z;
    }
    #pragma unroll
    for (int kt = 0; kt < KT; ++kt) {
        bf16x8 pf = *(const bf16x8*)&pw[l16 * PST + kt * 32 + quad * 8];
        #pragma unroll
        for (int n4 = 0; n4 < 4; ++n4) {
            const bf16* vp = vt + ((size_t)b * 512 + h * 64 + n4 * 16 + l16) * 240
                              + OFF + kt * 32 + quad * 8;
            bf16x8 vf = *(const bf16x8*)vp;
            oacc[n4] = __builtin_amdgcn_mfma_f32_16x16x32_bf16(pf, vf, oacc[n4], 0, 0, 0);
        }
    }
    #pragma unroll
    for (int n4 = 0; n4 < 4; ++n4)
        #pragma unroll
        for (int r = 0; r < 4; ++r)
            o[obase + (size_t)(slab * 16 + quad * 4 + r) * 512 + n4 * 16 + l16] =
                __float2bfloat16(oacc[n4][r]);
}

// ---------------------------------------------------------------- residual + layernorm (row = 512)
__global__ __launch_bounds__(256) void ln_kernel(const bf16* x, const bf16* res,
                                                 const float* __restrict__ g,
                                                 const float* __restrict__ bta,
                                                 bf16* out_bf, float* out_f) {
    int row = blockIdx.x;
    int t = threadIdx.x;
    const bf16* xr = x + (size_t)row * 512;
    float v0 = __bfloat162float(xr[t]);
    float v1 = __bfloat162float(xr[t + 256]);
    if (res) {
        const bf16* rr = res + (size_t)row * 512;
        v0 += __bfloat162float(rr[t]);
        v1 += __bfloat162float(rr[t + 256]);
    }
    float s = v0 + v1, ss = v0 * v0 + v1 * v1;
    #pragma unroll
    for (int mk = 1; mk < 64; mk <<= 1) { s += __shfl_xor(s, mk); ss += __shfl_xor(ss, mk); }
    __shared__ float red[8];
    int wave = t >> 6, lane = t & 63;
    if (lane == 0) { red[wave * 2] = s; red[wave * 2 + 1] = ss; }
    __syncthreads();
    s = red[0] + red[2] + red[4] + red[6];
    ss = red[1] + red[3] + red[5] + red[7];
    float mu = s * (1.f / 512.f);
    float var = ss * (1.f / 512.f) - mu * mu;
    float inv = rsqrtf(var + 1e-5f);
    float y0 = (v0 - mu) * inv * g[t] + bta[t];
    float y1 = (v1 - mu) * inv * g[t + 256] + bta[t + 256];
    if (out_bf) {
        bf16* orow = out_bf + (size_t)row * 512;
        orow[t] = __float2bfloat16(y0);
        orow[t + 256] = __float2bfloat16(y1);
    } else {
        float* orow = out_f + (size_t)row * 512;
        orow[t] = y0;
        orow[t + 256] = y1;
    }
}

// ---------------------------------------------------------------- launch
extern "C" void kernel_launch(void* const* d_in, const int* in_sizes, int n_in,
                              void* d_out, int out_size, void* d_ws, size_t ws_size,
                              hipStream_t stream) {
    const float* x_enc = (const float*)d_in[0];
    const float* W_emb = (const float*)d_in[1];
    const float* Wq    = (const float*)d_in[2];
    const float* bq    = (const float*)d_in[3];
    const float* Wk    = (const float*)d_in[4];
    const float* bk    = (const float*)d_in[5];
    const float* Wv    = (const float*)d_in[6];
    const float* bv    = (const float*)d_in[7];
    const float* Wo    = (const float*)d_in[8];
    const float* bo    = (const float*)d_in[9];
    const float* ln1_g = (const float*)d_in[10];
    const float* ln1_b = (const float*)d_in[11];
    const float* W1    = (const float*)d_in[12];
    const float* b1    = (const float*)d_in[13];
    const float* W2    = (const float*)d_in[14];
    const float* b2    = (const float*)d_in[15];
    const float* ln2_g = (const float*)d_in[16];
    const float* ln2_b = (const float*)d_in[17];
    const float* lnf_g = (const float*)d_in[18];
    const float* lnf_b = (const float*)d_in[19];

    const int ROWS = 256 * 240;            // 61440
    char* ws = (char*)d_ws;
    const size_t Hb = (size_t)ROWS * 512 * 2;  // 62,914,560 B
    bf16* h    = (bf16*)(ws);
    bf16* qkv  = (bf16*)(ws + Hb);         // [ROWS][1536]; q|k|v
    bf16* oa   = (bf16*)(ws + 4 * Hb);     // attention output [ROWS][512]
    bf16* scr2 = (bf16*)(ws + 5 * Hb);     // vt during attn; oproj; ffnout
    bf16* mid  = qkv;                      // FFN mid [ROWS][2048] aliases qkv+oa (4*Hb)
    bf16* WqkvT = (bf16*)(ws + 6 * Hb);    // [L][1536][512]
    bf16* WoT  = WqkvT + (size_t)3 * 1536 * 512;
    bf16* W1T  = WoT + (size_t)3 * 512 * 512;
    bf16* W2T  = W1T + (size_t)3 * 512 * 2048;
    float* bcat = (float*)(W2T + (size_t)3 * 2048 * 512);   // [L][1536]

    bf16* vt     = scr2;
    bf16* oproj  = scr2;
    bf16* ffnout = scr2;

    dim3 blk(256);
    transpose_f32_bf16<<<dim3(16, 16, 3), blk, 0, stream>>>(Wq, WqkvT, 512, 512, (size_t)1536 * 512);
    transpose_f32_bf16<<<dim3(16, 16, 3), blk, 0, stream>>>(Wk, WqkvT + (size_t)512 * 512, 512, 512, (size_t)1536 * 512);
    transpose_f32_bf16<<<dim3(16, 16, 3), blk, 0, stream>>>(Wv, WqkvT + (size_t)1024 * 512, 512, 512, (size_t)1536 * 512);
    transpose_f32_bf16<<<dim3(16, 16, 3), blk, 0, stream>>>(Wo, WoT, 512, 512, (size_t)512 * 512);
    transpose_f32_bf16<<<dim3(64, 16, 3), blk, 0, stream>>>(W1, W1T, 512, 2048, (size_t)512 * 2048);
    transpose_f32_bf16<<<dim3(16, 64, 3), blk, 0, stream>>>(W2, W2T, 2048, 512, (size_t)2048 * 512);
    concat_bias<<<18, blk, 0, stream>>>(bq, bk, bv, bcat);

    embed_kernel<<<ROWS, blk, 0, stream>>>(x_enc, W_emb, h);

    for (int L = 0; L < 3; ++L) {
        size_t wo = (size_t)L * 512 * 512;
        size_t w1o = (size_t)L * 512 * 2048;
        gemm_bt<<<dim3(12, 480), blk, 0, stream>>>(h, WqkvT + (size_t)L * 1536 * 512,
                                                   bcat + L * 1536, qkv, ROWS, 1536, 512, 0);
        transpose_v<<<dim3(16, 8, 256), blk, 0, stream>>>(qkv, vt);
        attn_mfma<16><<<512, blk, 0, stream>>>(qkv, vt, oa);
        attn_mfma<32><<<1024, blk, 0, stream>>>(qkv, vt, oa);
        attn_mfma<64><<<2048, blk, 0, stream>>>(qkv, vt, oa);
        attn_mfma<128><<<4096, blk, 0, stream>>>(qkv, vt, oa);
        gemm_bt<<<dim3(4, 480), blk, 0, stream>>>(oa, WoT + wo, bo + L * 512, oproj, ROWS, 512, 512, 0);
        ln_kernel<<<ROWS, blk, 0, stream>>>(h, oproj, ln1_g + L * 512, ln1_b + L * 512, h, nullptr);
        gemm_bt<<<dim3(16, 480), blk, 0, stream>>>(h, W1T + w1o, b1 + L * 2048, mid, ROWS, 2048, 512, 1);
        gemm_bt<<<dim3(4, 480), blk, 0, stream>>>(mid, W2T + w1o, b2 + L * 512, ffnout, ROWS, 512, 2048, 0);
        ln_kernel<<<ROWS, blk, 0, stream>>>(h, ffnout, ln2_g + L * 512, ln2_b + L * 512, h, nullptr);
    }
    ln_kernel<<<ROWS, blk, 0, stream>>>(h, nullptr, lnf_g, lnf_b, nullptr, (float*)d_out);
}

// Round 5
// 2966.873 us; speedup vs baseline: 2.0215x; 1.0788x over previous
//
#include <hip/hip_runtime.h>
#include <hip/hip_bf16.h>

typedef short bf16x8 __attribute__((ext_vector_type(8)));
typedef float f32x4 __attribute__((ext_vector_type(4)));
using bf16 = __hip_bfloat16;

#define GLOBAL_LOAD_LDS16(g, l)                                                          \
    __builtin_amdgcn_global_load_lds((const __attribute__((address_space(1))) unsigned int*)(g), \
                                     (__attribute__((address_space(3))) unsigned int*)(l), \
                                     16, 0, 0)

// ---------------------------------------------------------------- utilities
// gelu(x) = 0.5x(1+tanh(0.79788456x(1+0.044715x^2))) = x * sigmoid(1.5957691x(1+0.044715x^2))
static __device__ __forceinline__ float gelu_f(float x) {
    float u = 1.5957691216057308f * x * (1.0f + 0.044715f * x * x);
    return x / (1.0f + __expf(-u));
}

static __device__ __forceinline__ unsigned pack_bf16(float lo, float hi) {
    union { bf16 h; unsigned short u; } a, b;
    a.h = __float2bfloat16(lo);
    b.h = __float2bfloat16(hi);
    return ((unsigned)b.u << 16) | (unsigned)a.u;
}

// ---------------------------------------------------------------- transpose + downcast (f32 -> bf16), batched over z
__global__ __launch_bounds__(256) void transpose_f32_bf16(const float* __restrict__ in,
                                                          bf16* __restrict__ out,
                                                          int R, int C, size_t zso) {
    __shared__ float tile[32][33];
    size_t zi = (size_t)blockIdx.z * R * C;
    size_t zo = (size_t)blockIdx.z * zso;
    int c0 = blockIdx.x * 32, r0 = blockIdx.y * 32;
    int tx = threadIdx.x & 31, ty = threadIdx.x >> 5;
    #pragma unroll
    for (int i = 0; i < 32; i += 8) {
        int r = r0 + ty + i, c = c0 + tx;
        if (r < R && c < C) tile[ty + i][tx] = in[zi + (size_t)r * C + c];
    }
    __syncthreads();
    #pragma unroll
    for (int i = 0; i < 32; i += 8) {
        int c = c0 + ty + i, r = r0 + tx;
        if (c < C && r < R) out[zo + (size_t)c * R + r] = __float2bfloat16(tile[tx][ty + i]);
    }
}

// ---------------------------------------------------------------- bias concat: [L][1536] = bq|bk|bv
__global__ __launch_bounds__(256) void concat_bias(const float* __restrict__ bq,
                                                   const float* __restrict__ bk,
                                                   const float* __restrict__ bv,
                                                   float* __restrict__ out) {
    int i = blockIdx.x * 256 + threadIdx.x;
    if (i < 3 * 1536) {
        int L = i / 1536, r = i - L * 1536;
        float v = (r < 512) ? bq[L * 512 + r]
                : (r < 1024) ? bk[L * 512 + r - 512]
                             : bv[L * 512 + r - 1024];
        out[i] = v;
    }
}

// ---------------------------------------------------------------- V transpose: qkv[b*240+t][1536] (cols 1024..1535) -> vt[b*512+d][240]
__global__ __launch_bounds__(256) void transpose_v(const bf16* __restrict__ in,
                                                   bf16* __restrict__ out) {
    __shared__ bf16 tile[32][33];
    int b = blockIdx.z;
    int d0 = blockIdx.x * 32, t0 = blockIdx.y * 32;
    int tx = threadIdx.x & 31, ty = threadIdx.x >> 5;
    #pragma unroll
    for (int i = 0; i < 32; i += 8) {
        int tt = t0 + ty + i, dd = d0 + tx;
        if (tt < 240) tile[ty + i][tx] = in[((size_t)b * 240 + tt) * 1536 + 1024 + dd];
    }
    __syncthreads();
    #pragma unroll
    for (int i = 0; i < 32; i += 8) {
        int dd = d0 + ty + i, tt = t0 + tx;
        if (tt < 240) out[((size_t)b * 512 + dd) * 240 + tt] = tile[tx][ty + i];
    }
}

// ---------------------------------------------------------------- patch embedding + positional encoding
__global__ __launch_bounds__(256) void embed_kernel(const float* __restrict__ x_enc,
                                                    const float* __restrict__ W_emb, // [16][512]
                                                    bf16* __restrict__ h) {
    int row = blockIdx.x;
    int b = row / 240, l = row - b * 240;
    int s = (l < 16) ? 0 : (l < 48) ? 1 : (l < 112) ? 2 : 3;
    int len = 16 << s;
    int off = len - 16;           // 0,16,48,112
    int kk = 8 >> s;              // 8,4,2,1
    int j = l - off;
    int bs_i = b >> 5, c_i = b & 31;
    __shared__ float xv[16];
    int t = threadIdx.x;
    if (t < 16) {
        int tau = (j * 16 + t) * kk;
        xv[t] = x_enc[((size_t)bs_i * 2048 + tau) * 32 + c_i];
    }
    __syncthreads();
    int pe_row = j * kk;
    const float NEG2LN = -0.035977892078032f; // -2*ln(10000)/512
    for (int d = t; d < 512; d += 256) {
        float acc = 0.f;
        #pragma unroll
        for (int i = 0; i < 16; ++i) acc += xv[i] * W_emb[i * 512 + d];
        int di = d >> 1;
        float ang = (float)pe_row * expf((float)di * NEG2LN);
        float pos = (d & 1) ? cosf(ang) : sinf(ang);
        h[(size_t)row * 512 + d] = __float2bfloat16(acc + pos);
    }
}

// ---------------------------------------------------------------- GEMM: C[M,N] = A[M,K] @ Bt[N,K]^T + bias (+gelu)
// 128x128 tile, BK=64 (32 MFMA per barrier pair), global_load_lds width-16 staging,
// 3-bit XOR chunk swizzle (conflict-free b128 reads), paired-bf16 dword stores.
__global__ __launch_bounds__(256) void gemm_bt(const bf16* __restrict__ A,
                                               const bf16* __restrict__ Bt,
                                               const float* __restrict__ bias,
                                               bf16* __restrict__ C,
                                               int M, int N, int K, int act) {
    __shared__ __align__(16) bf16 smem[2 * 128 * 64];
    bf16* As = smem;
    bf16* Bs = smem + 128 * 64;
    const int t = threadIdx.x;
    const int wave = t >> 6, lane = t & 63;
    const int quad = lane >> 4, l16 = lane & 15;
    const int m0 = blockIdx.y * 128, n0 = blockIdx.x * 128;
    const int wm = (wave >> 1) * 64, wn = (wave & 1) * 64;

    f32x4 acc[4][4];
    #pragma unroll
    for (int a = 0; a < 4; ++a)
        #pragma unroll
        for (int b = 0; b < 4; ++b)
            #pragma unroll
            for (int r = 0; r < 4; ++r) acc[a][b][r] = 0.0f;

    const int srow = lane >> 3;            // row within 8-row group
    const int schunk = (lane & 7) ^ srow;  // permuted source chunk (16 B units)
    const bf16* Abase = A + (size_t)(m0 + wave * 32 + srow) * K + schunk * 8;
    const bf16* Bbase = Bt + (size_t)(n0 + wave * 32 + srow) * K + schunk * 8;

    for (int k0 = 0; k0 < K; k0 += 64) {
        __syncthreads();
        #pragma unroll
        for (int p = 0; p < 4; ++p) {
            GLOBAL_LOAD_LDS16(Abase + (size_t)p * 8 * K + k0, As + (wave * 4 + p) * 512);
            GLOBAL_LOAD_LDS16(Bbase + (size_t)p * 8 * K + k0, Bs + (wave * 4 + p) * 512);
        }
        __syncthreads();
        #pragma unroll
        for (int kt = 0; kt < 2; ++kt) {
            bf16x8 af[4], bfr[4];
            #pragma unroll
            for (int mi = 0; mi < 4; ++mi) {
                int row = wm + mi * 16 + l16;
                af[mi] = *(const bf16x8*)(&As[row * 64 + (((kt << 2) + quad) ^ (l16 & 7)) * 8]);
            }
            #pragma unroll
            for (int ni = 0; ni < 4; ++ni) {
                int row = wn + ni * 16 + l16;
                bfr[ni] = *(const bf16x8*)(&Bs[row * 64 + (((kt << 2) + quad) ^ (l16 & 7)) * 8]);
            }
            #pragma unroll
            for (int mi = 0; mi < 4; ++mi)
                #pragma unroll
                for (int ni = 0; ni < 4; ++ni)
                    acc[mi][ni] = __builtin_amdgcn_mfma_f32_16x16x32_bf16(af[mi], bfr[ni],
                                                                         acc[mi][ni], 0, 0, 0);
        }
    }

    // epilogue: adjacent l16 lanes hold adjacent cols of the same rows -> pair via shfl_xor(1),
    // store packed bf16x2 dwords (32 stores vs 64 short stores)
    const int oddl = l16 & 1;
    #pragma unroll
    for (int ni = 0; ni < 4; ++ni) {
        int col = n0 + wn + ni * 16 + l16;
        float bv = bias[col];
        #pragma unroll
        for (int mi = 0; mi < 4; ++mi) {
            float v0 = acc[mi][ni][0] + bv;
            float v1 = acc[mi][ni][1] + bv;
            float v2 = acc[mi][ni][2] + bv;
            float v3 = acc[mi][ni][3] + bv;
            if (act) {
                v0 = gelu_f(v0); v1 = gelu_f(v1);
                v2 = gelu_f(v2); v3 = gelu_f(v3);
            }
            float p0 = __shfl_xor(v0, 1);
            float p1 = __shfl_xor(v1, 1);
            float p2 = __shfl_xor(v2, 1);
            float p3 = __shfl_xor(v3, 1);
            float lo0 = oddl ? p1 : v0, hi0 = oddl ? v1 : p0;
            float lo1 = oddl ? p3 : v2, hi1 = oddl ? v3 : p2;
            int r0 = oddl ? 1 : 0;
            size_t rowb = (size_t)(m0 + wm + mi * 16 + quad * 4);
            unsigned* c0p = (unsigned*)(C + (rowb + r0) * N + (col & ~1));
            unsigned* c1p = (unsigned*)(C + (rowb + r0 + 2) * N + (col & ~1));
            *c0p = pack_bf16(lo0, hi0);
            *c1p = pack_bf16(lo1, hi1);
        }
    }
}

// ---------------------------------------------------------------- MFMA segment attention (qkv fused input, stride 1536)
template<int LEN>
__global__ __launch_bounds__(256) void attn_mfma(const bf16* __restrict__ qkv,
                                                 const bf16* __restrict__ vt,
                                                 bf16* __restrict__ o) {
    constexpr int NT = LEN / 16;
    constexpr int KT = (LEN >= 32) ? (LEN / 32) : 1;
    constexpr int PST = (LEN == 16) ? 40 : (LEN + 8);
    constexpr int SLABS = LEN / 16;
    constexpr int OFF = LEN - 16;
    __shared__ __align__(16) bf16 Plds[4 * 16 * PST];

    const int t = threadIdx.x;
    const int wave = t >> 6, lane = t & 63;
    const int quad = lane >> 4, l16 = lane & 15;
    const int task = blockIdx.x * 4 + wave;
    const int b = task / (8 * SLABS);
    const int rem = task - b * (8 * SLABS);
    const int h = rem / SLABS;
    const int slab = rem - h * SLABS;

    const size_t qbase = ((size_t)b * 240 + OFF) * 1536 + h * 64;
    const size_t obase = ((size_t)b * 240 + OFF) * 512 + h * 64;

    const bf16* qp = qkv + qbase + (size_t)(slab * 16 + l16) * 1536 + quad * 8;
    bf16x8 qf0 = *(const bf16x8*)qp;
    bf16x8 qf1 = *(const bf16x8*)(qp + 32);

    f32x4 sacc[NT];
    #pragma unroll
    for (int nt = 0; nt < NT; ++nt) {
        const bf16* kp = qkv + qbase + 512 + (size_t)(nt * 16 + l16) * 1536 + quad * 8;
        bf16x8 kf0 = *(const bf16x8*)kp;
        bf16x8 kf1 = *(const bf16x8*)(kp + 32);
        f32x4 a = {0.f, 0.f, 0.f, 0.f};
        a = __builtin_amdgcn_mfma_f32_16x16x32_bf16(qf0, kf0, a, 0, 0, 0);
        a = __builtin_amdgcn_mfma_f32_16x16x32_bf16(qf1, kf1, a, 0, 0, 0);
        sacc[nt] = a;
    }

    float mx[4], sm[4];
    #pragma unroll
    for (int r = 0; r < 4; ++r) mx[r] = -3.0e38f;
    #pragma unroll
    for (int nt = 0; nt < NT; ++nt)
        #pragma unroll
        for (int r = 0; r < 4; ++r) {
            sacc[nt][r] *= 0.125f;
            mx[r] = fmaxf(mx[r], sacc[nt][r]);
        }
    #pragma unroll
    for (int msk = 1; msk < 16; msk <<= 1)
        #pragma unroll
        for (int r = 0; r < 4; ++r) mx[r] = fmaxf(mx[r], __shfl_xor(mx[r], msk));
    #pragma unroll
    for (int r = 0; r < 4; ++r) sm[r] = 0.f;
    #pragma unroll
    for (int nt = 0; nt < NT; ++nt)
        #pragma unroll
        for (int r = 0; r < 4; ++r) {
            float p = __expf(sacc[nt][r] - mx[r]);
            sacc[nt][r] = p;
            sm[r] += p;
        }
    #pragma unroll
    for (int msk = 1; msk < 16; msk <<= 1)
        #pragma unroll
        for (int r = 0; r < 4; ++r) sm[r] += __shfl_xor(sm[r], msk);
    float inv[4];
    #pragma unroll
    for (int r = 0; r < 4; ++r) inv[r] = 1.f / sm[r];

    bf16* pw = Plds + wave * 16 * PST;
    #pragma unroll
    for (int nt = 0; nt < NT; ++nt)
        #pragma unroll
        for (int r = 0; r < 4; ++r)
            pw[(quad * 4 + r) * PST + nt * 16 + l16] =
                __float2bfloat16(sacc[nt][r] * inv[r]);
    if (LEN == 16) {
        #pragma unroll
        for (int r = 0; r < 4; ++r)
            pw[(quad * 4 + r) * PST + 16 + l16] = __float2bfloat16(0.f);
    }
    __syncthreads();

    f32x4 oacc[4];
    #pragma unroll
    for (int n4 = 0; n4 < 4; ++n4) {
        f32x4 z = {0.f, 0.f, 0.f, 0.f};
        oacc[n4] = z;
    }
    #pragma unroll
    for (int kt = 0; kt < KT; ++kt) {
        bf16x8 pf = *(const bf16x8*)&pw[l16 * PST + kt * 32 + quad * 8];
        #pragma unroll
        for (int n4 = 0; n4 < 4; ++n4) {
            const bf16* vp = vt + ((size_t)b * 512 + h * 64 + n4 * 16 + l16) * 240
                              + OFF + kt * 32 + quad * 8;
            bf16x8 vf = *(const bf16x8*)vp;
            oacc[n4] = __builtin_amdgcn_mfma_f32_16x16x32_bf16(pf, vf, oacc[n4], 0, 0, 0);
        }
    }
    #pragma unroll
    for (int n4 = 0; n4 < 4; ++n4)
        #pragma unroll
        for (int r = 0; r < 4; ++r)
            o[obase + (size_t)(slab * 16 + quad * 4 + r) * 512 + n4 * 16 + l16] =
                __float2bfloat16(oacc[n4][r]);
}

// ---------------------------------------------------------------- residual + layernorm (row = 512)
__global__ __launch_bounds__(256) void ln_kernel(const bf16* x, const bf16* res,
                                                 const float* __restrict__ g,
                                                 const float* __restrict__ bta,
                                                 bf16* out_bf, float* out_f) {
    int row = blockIdx.x;
    int t = threadIdx.x;
    const bf16* xr = x + (size_t)row * 512;
    float v0 = __bfloat162float(xr[t]);
    float v1 = __bfloat162float(xr[t + 256]);
    if (res) {
        const bf16* rr = res + (size_t)row * 512;
        v0 += __bfloat162float(rr[t]);
        v1 += __bfloat162float(rr[t + 256]);
    }
    float s = v0 + v1, ss = v0 * v0 + v1 * v1;
    #pragma unroll
    for (int mk = 1; mk < 64; mk <<= 1) { s += __shfl_xor(s, mk); ss += __shfl_xor(ss, mk); }
    __shared__ float red[8];
    int wave = t >> 6, lane = t & 63;
    if (lane == 0) { red[wave * 2] = s; red[wave * 2 + 1] = ss; }
    __syncthreads();
    s = red[0] + red[2] + red[4] + red[6];
    ss = red[1] + red[3] + red[5] + red[7];
    float mu = s * (1.f / 512.f);
    float var = ss * (1.f / 512.f) - mu * mu;
    float inv = rsqrtf(var + 1e-5f);
    float y0 = (v0 - mu) * inv * g[t] + bta[t];
    float y1 = (v1 - mu) * inv * g[t + 256] + bta[t + 256];
    if (out_bf) {
        bf16* orow = out_bf + (size_t)row * 512;
        orow[t] = __float2bfloat16(y0);
        orow[t + 256] = __float2bfloat16(y1);
    } else {
        float* orow = out_f + (size_t)row * 512;
        orow[t] = y0;
        orow[t + 256] = y1;
    }
}

// ---------------------------------------------------------------- launch
extern "C" void kernel_launch(void* const* d_in, const int* in_sizes, int n_in,
                              void* d_out, int out_size, void* d_ws, size_t ws_size,
                              hipStream_t stream) {
    const float* x_enc = (const float*)d_in[0];
    const float* W_emb = (const float*)d_in[1];
    const float* Wq    = (const float*)d_in[2];
    const float* bq    = (const float*)d_in[3];
    const float* Wk    = (const float*)d_in[4];
    const float* bk    = (const float*)d_in[5];
    const float* Wv    = (const float*)d_in[6];
    const float* bv    = (const float*)d_in[7];
    const float* Wo    = (const float*)d_in[8];
    const float* bo    = (const float*)d_in[9];
    const float* ln1_g = (const float*)d_in[10];
    const float* ln1_b = (const float*)d_in[11];
    const float* W1    = (const float*)d_in[12];
    const float* b1    = (const float*)d_in[13];
    const float* W2    = (const float*)d_in[14];
    const float* b2    = (const float*)d_in[15];
    const float* ln2_g = (const float*)d_in[16];
    const float* ln2_b = (const float*)d_in[17];
    const float* lnf_g = (const float*)d_in[18];
    const float* lnf_b = (const float*)d_in[19];

    const int ROWS = 256 * 240;            // 61440
    char* ws = (char*)d_ws;
    const size_t Hb = (size_t)ROWS * 512 * 2;  // 62,914,560 B
    bf16* h    = (bf16*)(ws);
    bf16* qkv  = (bf16*)(ws + Hb);         // [ROWS][1536]; q|k|v
    bf16* oa   = (bf16*)(ws + 4 * Hb);     // attention output [ROWS][512]
    bf16* scr2 = (bf16*)(ws + 5 * Hb);     // vt during attn; oproj; ffnout
    bf16* mid  = qkv;                      // FFN mid [ROWS][2048] aliases qkv+oa (4*Hb)
    bf16* WqkvT = (bf16*)(ws + 6 * Hb);    // [L][1536][512]
    bf16* WoT  = WqkvT + (size_t)3 * 1536 * 512;
    bf16* W1T  = WoT + (size_t)3 * 512 * 512;
    bf16* W2T  = W1T + (size_t)3 * 512 * 2048;
    float* bcat = (float*)(W2T + (size_t)3 * 2048 * 512);   // [L][1536]

    bf16* vt     = scr2;
    bf16* oproj  = scr2;
    bf16* ffnout = scr2;

    dim3 blk(256);
    transpose_f32_bf16<<<dim3(16, 16, 3), blk, 0, stream>>>(Wq, WqkvT, 512, 512, (size_t)1536 * 512);
    transpose_f32_bf16<<<dim3(16, 16, 3), blk, 0, stream>>>(Wk, WqkvT + (size_t)512 * 512, 512, 512, (size_t)1536 * 512);
    transpose_f32_bf16<<<dim3(16, 16, 3), blk, 0, stream>>>(Wv, WqkvT + (size_t)1024 * 512, 512, 512, (size_t)1536 * 512);
    transpose_f32_bf16<<<dim3(16, 16, 3), blk, 0, stream>>>(Wo, WoT, 512, 512, (size_t)512 * 512);
    transpose_f32_bf16<<<dim3(64, 16, 3), blk, 0, stream>>>(W1, W1T, 512, 2048, (size_t)512 * 2048);
    transpose_f32_bf16<<<dim3(16, 64, 3), blk, 0, stream>>>(W2, W2T, 2048, 512, (size_t)2048 * 512);
    concat_bias<<<18, blk, 0, stream>>>(bq, bk, bv, bcat);

    embed_kernel<<<ROWS, blk, 0, stream>>>(x_enc, W_emb, h);

    for (int L = 0; L < 3; ++L) {
        size_t wo = (size_t)L * 512 * 512;
        size_t w1o = (size_t)L * 512 * 2048;
        gemm_bt<<<dim3(12, 480), blk, 0, stream>>>(h, WqkvT + (size_t)L * 1536 * 512,
                                                   bcat + L * 1536, qkv, ROWS, 1536, 512, 0);
        transpose_v<<<dim3(16, 8, 256), blk, 0, stream>>>(qkv, vt);
        attn_mfma<16><<<512, blk, 0, stream>>>(qkv, vt, oa);
        attn_mfma<32><<<1024, blk, 0, stream>>>(qkv, vt, oa);
        attn_mfma<64><<<2048, blk, 0, stream>>>(qkv, vt, oa);
        attn_mfma<128><<<4096, blk, 0, stream>>>(qkv, vt, oa);
        gemm_bt<<<dim3(4, 480), blk, 0, stream>>>(oa, WoT + wo, bo + L * 512, oproj, ROWS, 512, 512, 0);
        ln_kernel<<<ROWS, blk, 0, stream>>>(h, oproj, ln1_g + L * 512, ln1_b + L * 512, h, nullptr);
        gemm_bt<<<dim3(16, 480), blk, 0, stream>>>(h, W1T + w1o, b1 + L * 2048, mid, ROWS, 2048, 512, 1);
        gemm_bt<<<dim3(4, 480), blk, 0, stream>>>(mid, W2T + w1o, b2 + L * 512, ffnout, ROWS, 512, 2048, 0);
        ln_kernel<<<ROWS, blk, 0, stream>>>(h, ffnout, ln2_g + L * 512, ln2_b + L * 512, h, nullptr);
    }
    ln_kernel<<<ROWS, blk, 0, stream>>>(h, nullptr, lnf_g, lnf_b, nullptr, (float*)d_out);
}